// Round 4
// baseline (687.680 us; speedup 1.0000x reference)
//
#include <hip/hip_runtime.h>
#include <stdint.h>

#define NPTS 131072
#define CINC 128
#define COUTC 128
#define WDIM 512
#define K3 27
#define CAP 48

typedef float f32x4 __attribute__((ext_vector_type(4)));
typedef __bf16 bf16x8 __attribute__((ext_vector_type(8)));

__device__ __forceinline__ unsigned short f2bf(float x){
  union { float f; uint32_t u; } v; v.f = x;
  uint32_t u = v.u;
  uint32_t r = (u + 0x7fffu + ((u >> 16) & 1u)) >> 16;
  return (unsigned short)r;
}

// styles[b*128+c] = dot(w[b], aw[c])/sqrt(512) + ab[c]; one dot per wave
__global__ void k_styles_dot(const float* __restrict__ w, const float* __restrict__ aw,
                             const float* __restrict__ ab, float* __restrict__ styles){
  int wave = threadIdx.x >> 6, lane = threadIdx.x & 63;
  int blk = blockIdx.x * 4 + wave;
  int b = blk >> 7, c = blk & 127;
  const float4* wr = (const float4*)(w + b * WDIM);
  const float4* ar = (const float4*)(aw + c * WDIM);
  float4 w0 = wr[lane * 2], w1 = wr[lane * 2 + 1];
  float4 a0 = ar[lane * 2], a1 = ar[lane * 2 + 1];
  float s = w0.x * a0.x + w0.y * a0.y + w0.z * a0.z + w0.w * a0.w
          + w1.x * a1.x + w1.y * a1.y + w1.z * a1.z + w1.w * a1.w;
  for (int off = 32; off > 0; off >>= 1) s += __shfl_down(s, off, 64);
  if (lane == 0) styles[blk] = s * 0.04419417382415922f + ab[c];
}

// sn = styles * rsqrt(mean(styles^2))
__global__ void k_snorm(const float* __restrict__ styles, float* __restrict__ sn){
  __shared__ float red[512];
  int t = threadIdx.x;
  float s = styles[t];
  red[t] = s * s;
  __syncthreads();
  for (int off = 256; off > 0; off >>= 1){
    if (t < off) red[t] += red[t + off];
    __syncthreads();
  }
  sn[t] = s * rsqrtf(red[0] * (1.0f / 512.0f));
}

// per cout: wnorm + vmat[cout][cin]=sum_k cw^2 + bpack (MFMA frag layout, wn-scaled)
// bpack[((k*32 + kk*8 + grp)*64 + q*16 + m)*8 + j] = wn[cout=grp*16+m][cin=kk*32+q*8+j][k]
__global__ void k_prep_w(const float* __restrict__ cw, float* __restrict__ wnorm,
                         float* __restrict__ vmat, unsigned short* __restrict__ bpack){
  __shared__ float red[128];
  int co = blockIdx.x, cin = threadIdx.x;
  const float* p = cw + co * 3456 + cin * 27;
  float r[27];
  float v = 0.f;
  #pragma unroll
  for (int k = 0; k < 27; k++){ r[k] = p[k]; v += r[k] * r[k]; }
  vmat[co * 128 + cin] = v;
  red[cin] = v;
  __syncthreads();
  for (int off = 64; off > 0; off >>= 1){
    if (cin < off) red[cin] += red[cin + off];
    __syncthreads();
  }
  float wn_s = rsqrtf(red[0] * (1.0f / 3456.0f));
  if (cin == 0) wnorm[co] = wn_s;
  int grp = co >> 4, m = co & 15;
  int kk = cin >> 5, q = (cin >> 3) & 3, j = cin & 7;
  #pragma unroll
  for (int k = 0; k < 27; k++){
    int idx = ((k * 32 + kk * 8 + grp) * 64 + q * 16 + m) * 8 + j;
    bpack[idx] = f2bf(r[k] * wn_s);
  }
}

__global__ void k_dcoefs2(const float* __restrict__ vmat, const float* __restrict__ sn,
                          const float* __restrict__ wnorm, const float* __restrict__ mag,
                          float* __restrict__ dco2){
  int wave = threadIdx.x >> 6, lane = threadIdx.x & 63;
  int pair = blockIdx.x * 8 + wave;
  int b = pair >> 7, co = pair & 127;
  float s0 = sn[b * 128 + lane], s1 = sn[b * 128 + 64 + lane];
  float sum = vmat[co * 128 + lane] * s0 * s0 + vmat[co * 128 + 64 + lane] * s1 * s1;
  for (int off = 32; off > 0; off >>= 1) sum += __shfl_down(sum, off, 64);
  if (lane == 0){
    float wn = wnorm[co];
    dco2[pair] = rsqrtf(sum * wn * wn + 1e-8f) * rsqrtf(mag[0]);
  }
}

// xpad[n][c] = bf16(x[n][c] * sn[b][c]); row NPTS = zeros. 16B stores.
__global__ void k_xmod(const float* __restrict__ x, const float* __restrict__ sn,
                       const int* __restrict__ bidx, unsigned short* __restrict__ xpad){
  int gid = blockIdx.x * 256 + threadIdx.x;
  const int total = (NPTS + 1) * 16;
  if (gid >= total) return;
  int n = gid >> 4, c8 = (gid & 15) * 8;
  uint32_t u0 = 0, u1 = 0, u2 = 0, u3 = 0;
  if (n < NPTS){
    int b = bidx[n];
    float4 x0 = *(const float4*)(x + (size_t)n * CINC + c8);
    float4 x1 = *(const float4*)(x + (size_t)n * CINC + c8 + 4);
    float4 s0 = *(const float4*)(sn + b * CINC + c8);
    float4 s1 = *(const float4*)(sn + b * CINC + c8 + 4);
    u0 = (uint32_t)f2bf(x0.x * s0.x) | ((uint32_t)f2bf(x0.y * s0.y) << 16);
    u1 = (uint32_t)f2bf(x0.z * s0.z) | ((uint32_t)f2bf(x0.w * s0.w) << 16);
    u2 = (uint32_t)f2bf(x1.x * s1.x) | ((uint32_t)f2bf(x1.y * s1.y) << 16);
    u3 = (uint32_t)f2bf(x1.z * s1.z) | ((uint32_t)f2bf(x1.w * s1.w) << 16);
  }
  int4 v = make_int4((int)u0, (int)u1, (int)u2, (int)u3);
  *(int4*)(xpad + (size_t)n * CINC + c8) = v;
}

// init cnt=0, pairs = (slot<<20)|NPTS  (pad slots: distinct lo rows, zero input row)
__global__ void k_zero(unsigned int* __restrict__ cnt, unsigned int* __restrict__ pairs){
  int gid = blockIdx.x * 256 + threadIdx.x;
  if (gid < 1024 * 27) cnt[gid] = 0u;
  const int total = 1024 * 27 * CAP;
  if (gid < total){
    unsigned int slot = (unsigned int)(gid % CAP);
    pairs[gid] = (slot << 20) | (unsigned int)NPTS;
  }
}

// scatter valid (out,in) pairs into per-(block,tap) compacted lists
__global__ void k_pairs(const int* __restrict__ out_idx, const int* __restrict__ in_idx,
                        unsigned int* __restrict__ cnt, unsigned int* __restrict__ pairs){
  int k = blockIdx.y;
  if (k == 13) return;                       // center tap = identity, no list
  int j = blockIdx.x * 256 + threadIdx.x;
  int o = out_idx[(size_t)k * NPTS + j];
  if (o >= NPTS) return;
  int in = in_idx[(size_t)k * NPTS + j];
  int b = o >> 7, lo = o & 127;
  unsigned int slot = atomicAdd(&cnt[b * 27 + k], 1u);
  if (slot < CAP)
    pairs[((size_t)(b * 27 + k)) * CAP + slot] = ((unsigned int)lo << 20) | (unsigned int)in;
}

// Sparse conv: block = 128 out rows x 128 couts. 8 waves = (cout-half h) x (tap-group g).
// LDS = 128x129 fp32 out-accumulator only. W-frags in regs (MFMA A-operand -> D[cout][slot]),
// X-frags gathered direct from global, accumulation via ds_add_f32. No mid-loop barriers.
__global__ __launch_bounds__(512, 2) void k_conv(
    const unsigned short* __restrict__ xpad,
    const unsigned short* __restrict__ bpack,
    const unsigned int* __restrict__ pairs,
    const unsigned int* __restrict__ cnt,
    const float* __restrict__ dco2,
    const float* __restrict__ cbias,
    const int* __restrict__ bidx,
    float* __restrict__ out){
  __shared__ float oacc[128 * 129];          // 66048 B, stride-129 spreads atomic banks
  int t = threadIdx.x;
  #pragma unroll
  for (int i = 0; i < 33; i++){
    int idx = i * 512 + t;
    if (idx < 128 * 129) oacc[idx] = 0.f;
  }
  __syncthreads();

  int wave = t >> 6, lane = t & 63;
  int h = wave & 1, g = wave >> 1;           // h: cout half (64), g: tap group (0..3)
  int q = lane >> 4, m16 = lane & 15;
  int base = blockIdx.x * 128;
  const unsigned int* cntb = cnt + blockIdx.x * 27;

  for (int k = 0; k < K3; k++){
    int ntiles;
    bool center = (k == 13);
    if (center){
      ntiles = 2;                            // tiles g*2, g*2+1 (8 total across groups)
    } else {
      int sidx = k - (k > 13 ? 1 : 0);
      if ((sidx & 3) != g) continue;         // wave-uniform tap ownership
      int c = (int)cntb[k];
      if (c == 0) continue;
      ntiles = (c + 15) >> 4; if (ntiles > 3) ntiles = 3;
    }
    // W fragments for this tap, wave's 64 couts: A-operand layout == bpack layout
    const unsigned short* bp = bpack + (size_t)k * 16384 + ((size_t)(h * 4) * 64 + lane) * 8;
    bf16x8 Wf[4][4];                          // [kk][cg]
    #pragma unroll
    for (int kk = 0; kk < 4; kk++)
      #pragma unroll
      for (int cg = 0; cg < 4; cg++)
        Wf[kk][cg] = *(const bf16x8*)(bp + (size_t)(kk * 8 + cg) * 512);

    const unsigned int* pl = pairs + ((size_t)blockIdx.x * 27 + k) * CAP;
    for (int tt = 0; tt < ntiles; tt++){
      int lo, in;
      if (center){
        int tti = g * 2 + tt;
        lo = tti * 16 + m16; in = base + lo;
      } else {
        unsigned int p = pl[tt * 16 + m16];  // slot = m16 (4 q-lanes broadcast)
        in = (int)(p & 0xFFFFFu); lo = (int)(p >> 20);
      }
      const unsigned short* xr = xpad + (size_t)in * CINC + q * 8;
      bf16x8 X0 = *(const bf16x8*)(xr);
      bf16x8 X1 = *(const bf16x8*)(xr + 32);
      bf16x8 X2 = *(const bf16x8*)(xr + 64);
      bf16x8 X3 = *(const bf16x8*)(xr + 96);
      float* orow = oacc + lo * 129 + h * 64;
      #pragma unroll
      for (int cg = 0; cg < 4; cg++){
        f32x4 D = (f32x4){0.f, 0.f, 0.f, 0.f};
        D = __builtin_amdgcn_mfma_f32_16x16x32_bf16(Wf[0][cg], X0, D, 0, 0, 0);
        D = __builtin_amdgcn_mfma_f32_16x16x32_bf16(Wf[1][cg], X1, D, 0, 0, 0);
        D = __builtin_amdgcn_mfma_f32_16x16x32_bf16(Wf[2][cg], X2, D, 0, 0, 0);
        D = __builtin_amdgcn_mfma_f32_16x16x32_bf16(Wf[3][cg], X3, D, 0, 0, 0);
        // D: col(lane&15)=slot, row(q*4+r)=cout within cg; per-lane row = lo[m16]
        #pragma unroll
        for (int r = 0; r < 4; r++)
          atomicAdd(orow + cg * 16 + q * 4 + r, D[r]);
      }
    }
  }

  __syncthreads();
  // epilogue: demod + bias + leaky*sqrt2 + clip
  const float S2 = 1.41421356237309515f;
  #pragma unroll
  for (int i = 0; i < 8; i++){
    int idx = i * 512 + t;
    int row = idx >> 5, c4 = (idx & 31) * 4;
    int n = base + row;
    int b = bidx[n];
    const float* dc = dco2 + b * COUTC + c4;
    const float* ob = oacc + row * 129 + c4;
    float4 bv = *(const float4*)(cbias + c4);
    float o0 = ob[0], o1 = ob[1], o2 = ob[2], o3 = ob[3];
    float4 v;
    v.x = o0 * dc[0] + bv.x;
    v.y = o1 * dc[1] + bv.y;
    v.z = o2 * dc[2] + bv.z;
    v.w = o3 * dc[3] + bv.w;
    v.x = fminf(fmaxf((v.x < 0.f ? 0.2f * v.x : v.x) * S2, -256.f), 256.f);
    v.y = fminf(fmaxf((v.y < 0.f ? 0.2f * v.y : v.y) * S2, -256.f), 256.f);
    v.z = fminf(fmaxf((v.z < 0.f ? 0.2f * v.z : v.z) * S2, -256.f), 256.f);
    v.w = fminf(fmaxf((v.w < 0.f ? 0.2f * v.w : v.w) * S2, -256.f), 256.f);
    *(float4*)(out + (size_t)n * COUTC + c4) = v;
  }
}

extern "C" void kernel_launch(void* const* d_in, const int* in_sizes, int n_in,
                              void* d_out, int out_size, void* d_ws, size_t ws_size,
                              hipStream_t stream){
  const float* x   = (const float*)d_in[0];
  const float* w   = (const float*)d_in[1];
  const float* aw  = (const float*)d_in[2];
  const float* ab  = (const float*)d_in[3];
  const float* cw  = (const float*)d_in[4];
  const float* cb  = (const float*)d_in[5];
  const float* mag = (const float*)d_in[6];
  const int* bidx    = (const int*)d_in[7];
  const int* in_idx  = (const int*)d_in[8];
  const int* out_idx = (const int*)d_in[9];
  float* out = (float*)d_out;
  char* ws = (char*)d_ws;

  float* styles = (float*)(ws + 0);          // 2048
  float* sn     = (float*)(ws + 2048);       // 2048
  float* wnorm  = (float*)(ws + 4096);       // 512
  float* dco2   = (float*)(ws + 4608);       // 2048 -> 6656
  float* vmat   = (float*)(ws + 8192);       // 65536 -> 73728
  unsigned short* bpack = (unsigned short*)(ws + 73728);    // 884736 -> 958464
  unsigned short* xpad  = (unsigned short*)(ws + 958464);   // 33554688 -> 34513152
  unsigned int* cnt     = (unsigned int*)(ws + 34513152);   // 110592 -> 34623744
  unsigned int* pairs   = (unsigned int*)(ws + 34623744);   // 5308416 -> 39932160

  k_prep_w<<<128, 128, 0, stream>>>(cw, wnorm, vmat, bpack);
  k_styles_dot<<<128, 256, 0, stream>>>(w, aw, ab, styles);
  k_snorm<<<1, 512, 0, stream>>>(styles, sn);
  k_dcoefs2<<<64, 512, 0, stream>>>(vmat, sn, wnorm, mag, dco2);
  k_xmod<<<8193, 256, 0, stream>>>(x, sn, bidx, xpad);
  k_zero<<<5184, 256, 0, stream>>>(cnt, pairs);
  dim3 gp(512, 27);
  k_pairs<<<gp, 256, 0, stream>>>(out_idx, in_idx, cnt, pairs);
  k_conv<<<1024, 512, 0, stream>>>(xpad, bpack, pairs, cnt, dco2, cb, bidx, out);
}